// Round 2
// baseline (815.729 us; speedup 1.0000x reference)
//
#include <hip/hip_runtime.h>
#include <math.h>

#define NPTS   131072
#define NB     32
#define HD     64
#define LIMIT  10.0f
#define CLAMPV 10000.0f

__global__ void zero_out_kernel(float* out) {
    out[0] = 0.0f;
}

__global__ __launch_bounds__(256) void realnvp_kernel(
    const float* __restrict__ x,
    const float* __restrict__ W1, const float* __restrict__ b1,
    const float* __restrict__ W2, const float* __restrict__ b2,
    const float* __restrict__ W3, const float* __restrict__ b3,
    const float* __restrict__ loc, const float* __restrict__ log_scale,
    float* __restrict__ out)
{
    __shared__ float red[4];

    const int tid = threadIdx.x;
    const int gid = blockIdx.x * 256 + tid;

    float za = x[2 * gid + 0];
    float zb = x[2 * gid + 1];
    float ld = 0.0f;
    bool mask = true;

    for (int t = 0; t < NB; ++t) {
        const int p = NB - 1 - t;   // params are reversed in the scan

        // All weight pointers/indices below are wave-uniform -> scalar loads
        const float* __restrict__ W1p = W1 + p * HD;
        const float* __restrict__ b1p = b1 + p * HD;
        const float* __restrict__ W2p = W2 + p * HD * HD;
        const float* __restrict__ b2p = b2 + p * HD;
        const float* __restrict__ W3p = W3 + p * 2 * HD;
        const float* __restrict__ b3p = b3 + p * 2;

        // --- permute step: z_out = clip(swap(z)); mask &= |z|<R
        bool in1 = (fabsf(za) < LIMIT) && (fabsf(zb) < LIMIT);
        mask = mask && in1;
        if (mask) {
            float na = fminf(fmaxf(zb, -CLAMPV), CLAMPV);
            float nb = fminf(fmaxf(za, -CLAMPV), CLAMPV);
            za = na; zb = nb;
        }

        // --- coupling inverse: MLP(z1) -> (shift, scale)
        const float z1 = za, z2 = zb;

        float h2[HD];
        {
            const float4* b2v = (const float4*)b2p;
            #pragma unroll
            for (int j4 = 0; j4 < HD / 4; ++j4) {
                float4 b = b2v[j4];
                h2[4 * j4 + 0] = b.x; h2[4 * j4 + 1] = b.y;
                h2[4 * j4 + 2] = b.z; h2[4 * j4 + 3] = b.w;
            }
        }

        for (int k = 0; k < HD; ++k) {
            float h1k = fmaxf(fmaf(z1, W1p[k], b1p[k]), 0.0f);
            const float4* row = (const float4*)(W2p + k * HD);  // 256B-aligned, uniform
            #pragma unroll
            for (int j4 = 0; j4 < HD / 4; ++j4) {
                float4 w = row[j4];   // uniform address -> s_load into SGPRs
                h2[4 * j4 + 0] = fmaf(h1k, w.x, h2[4 * j4 + 0]);
                h2[4 * j4 + 1] = fmaf(h1k, w.y, h2[4 * j4 + 1]);
                h2[4 * j4 + 2] = fmaf(h1k, w.z, h2[4 * j4 + 2]);
                h2[4 * j4 + 3] = fmaf(h1k, w.w, h2[4 * j4 + 3]);
            }
        }

        float shift = b3p[0], scale = b3p[1];
        #pragma unroll
        for (int j = 0; j < HD; ++j) {
            float hj = fmaxf(h2[j], 0.0f);   // relu of layer 2
            shift = fmaf(hj, W3p[2 * j + 0], shift);
            scale = fmaf(hj, W3p[2 * j + 1], scale);
        }

        float z2n = (z2 - shift) * __expf(-scale);

        // --- second mask check on post-permute z, then gated update
        bool in2 = (fabsf(za) < LIMIT) && (fabsf(zb) < LIMIT);
        mask = mask && in2;
        if (mask) {
            za = fminf(fmaxf(z1, -CLAMPV), CLAMPV);
            zb = fminf(fmaxf(z2n, -CLAMPV), CLAMPV);
            ld -= scale;
        }
    }

    // --- base log-prob
    const float l0 = loc[0], l1 = loc[1];
    const float ls0 = log_scale[0], ls1 = log_scale[1];
    const float e0 = __expf(-ls0), e1 = __expf(-ls1);
    const float t0 = (za - l0) * e0, t1 = (zb - l1) * e1;
    // -0.5*D*log(2*pi) with D=2
    float val = -1.8378770664093453f - (ls0 + ls1)
                - 0.5f * (t0 * t0 + t1 * t1) + ld;

    // --- reduction: wave shuffle -> LDS -> one atomic per workgroup
    #pragma unroll
    for (int off = 32; off > 0; off >>= 1)
        val += __shfl_down(val, off, 64);

    const int wave = tid >> 6;
    if ((tid & 63) == 0) red[wave] = val;
    __syncthreads();
    if (tid == 0) {
        float s = red[0] + red[1] + red[2] + red[3];
        atomicAdd(out, s);
    }
}

extern "C" void kernel_launch(void* const* d_in, const int* in_sizes, int n_in,
                              void* d_out, int out_size, void* d_ws, size_t ws_size,
                              hipStream_t stream) {
    const float* x   = (const float*)d_in[0];
    const float* W1  = (const float*)d_in[1];
    const float* b1  = (const float*)d_in[2];
    const float* W2  = (const float*)d_in[3];
    const float* b2  = (const float*)d_in[4];
    const float* W3  = (const float*)d_in[5];
    const float* b3  = (const float*)d_in[6];
    const float* loc = (const float*)d_in[7];
    const float* lsc = (const float*)d_in[8];
    float* out = (float*)d_out;

    zero_out_kernel<<<1, 1, 0, stream>>>(out);
    realnvp_kernel<<<NPTS / 256, 256, 0, stream>>>(
        x, W1, b1, W2, b2, W3, b3, loc, lsc, out);
}

// Round 3
// 350.733 us; speedup vs baseline: 2.3258x; 2.3258x over previous
//
#include <hip/hip_runtime.h>
#include <math.h>

#define NPTS   131072
#define NB     32
#define HD     64
#define NSEG   65            // 64 breakpoints -> 65 segments
#define LIMIT  10.0f
#define CLAMPV 10000.0f

// ws layout: tab[NB][NSEG][128]  (P[64] | Q[64]) then bounds[NB][64]
#define TAB_FLOATS   (NB * NSEG * 128)
#define BOUNDS_OFF   TAB_FLOATS

__global__ void zero_out_kernel(float* out) {
    out[0] = 0.0f;
}

// One workgroup per flow block: build piecewise-linear tables.
__global__ __launch_bounds__(256) void build_tables(
    const float* __restrict__ W1, const float* __restrict__ b1,
    const float* __restrict__ W2, const float* __restrict__ b2,
    float* __restrict__ ws)
{
    const int p = blockIdx.x;
    const int tid = threadIdx.x;

    __shared__ float w1s[HD], b1s[HD], b2s[HD];
    __shared__ float tr[HD];        // raw breakpoints
    __shared__ float ts[HD];        // sorted breakpoints
    __shared__ float zrep[NSEG];    // per-segment representative point
    __shared__ float W2s[HD * HD];  // 16 KB

    for (int i = tid; i < HD * HD; i += 256)
        W2s[i] = W2[p * HD * HD + i];
    if (tid < HD) {
        w1s[tid] = W1[p * HD + tid];
        b1s[tid] = b1[p * HD + tid];
        b2s[tid] = b2[p * HD + tid];
    }
    __syncthreads();

    if (tid < HD) {
        float w = w1s[tid], b = b1s[tid];
        float t = -b / w;                 // +-inf when w==0 (unit never crosses)
        if (!(t == t)) t = INFINITY;      // NaN (b=w=0) -> push to end
        tr[tid] = t;
    }
    __syncthreads();
    if (tid < HD) {                       // rank sort (stable)
        float v = tr[tid];
        int r = 0;
        for (int j = 0; j < HD; ++j) {
            float u = tr[j];
            r += (u < v) || (u == v && j < tid);
        }
        ts[r] = v;
    }
    __syncthreads();
    if (tid < NSEG) {                     // representative z per segment
        float lo = (tid == 0)  ? -3.0e38f : ts[tid - 1];
        float hi = (tid == HD) ?  3.0e38f : ts[tid];
        lo = fmaxf(lo, -1.0e20f);         // keep finite: avoid 0*inf NaN
        hi = fminf(hi,  1.0e20f);
        zrep[tid] = 0.5f * (lo + hi);
    }
    __syncthreads();

    float* tab = ws;
    for (int task = tid; task < NSEG * HD; task += 256) {
        const int s = task >> 6;
        const int j = task & (HD - 1);
        const float z = zrep[s];
        float Pv = 0.0f, Qv = b2s[j];
        for (int k = 0; k < HD; ++k) {
            float w = w1s[k], b = b1s[k];
            bool act = (fmaf(w, z, b) > 0.0f);
            float wij = W2s[k * HD + j];
            if (act) {
                Pv = fmaf(wij, w, Pv);
                Qv = fmaf(wij, b, Qv);
            }
        }
        const size_t base = ((size_t)p * NSEG + s) * 128;
        tab[base + j] = Pv;
        tab[base + 64 + j] = Qv;
    }
    if (tid < HD) ws[BOUNDS_OFF + p * HD + tid] = ts[tid];
}

// Two lanes per point (half = tid&1 handles 32 of 64 hidden channels).
__global__ __launch_bounds__(256) void realnvp_pwl(
    const float* __restrict__ x,
    const float* __restrict__ ws,
    const float* __restrict__ W3, const float* __restrict__ b3,
    const float* __restrict__ loc, const float* __restrict__ log_scale,
    float* __restrict__ out)
{
    __shared__ float bt[HD];
    __shared__ float w3s[2 * HD];
    __shared__ float b3s[2];
    __shared__ float red[4];

    const int tid  = threadIdx.x;
    const int half = tid & 1;
    const int g    = blockIdx.x * 128 + (tid >> 1);

    const float* tab = ws;

    float za = x[2 * g + 0];
    float zb = x[2 * g + 1];
    float ld = 0.0f;
    bool mask = true;

    for (int t = 0; t < NB; ++t) {
        const int p = NB - 1 - t;

        __syncthreads();
        if (tid < HD)     bt[tid]  = ws[BOUNDS_OFF + p * HD + tid];
        if (tid < 2 * HD) w3s[tid] = W3[p * 2 * HD + tid];
        if (tid < 2)      b3s[tid] = b3[p * 2 + tid];
        __syncthreads();

        // permute step
        bool in1 = (fabsf(za) < LIMIT) && (fabsf(zb) < LIMIT);
        mask = mask && in1;
        if (mask) {
            float na = fminf(fmaxf(zb, -CLAMPV), CLAMPV);
            float nb = fminf(fmaxf(za, -CLAMPV), CLAMPV);
            za = na; zb = nb;
        }

        const float z1 = za, z2 = zb;

        // segment = #breakpoints < z1 (binary count over sorted bt[64])
        int s = 0;
        #pragma unroll
        for (int st = 32; st > 0; st >>= 1)
            if (bt[s + st - 1] < z1) s += st;

        const float4* rowP = (const float4*)(tab + ((size_t)(p * NSEG + s)) * 128);
        const float4* rowQ = rowP + 16;
        const float4* w3v  = (const float4*)w3s;

        float sh = 0.0f, sc = 0.0f;
        const int j0 = half * 8;
        #pragma unroll
        for (int q = 0; q < 8; ++q) {
            float4 Pv = rowP[j0 + q];
            float4 Qv = rowQ[j0 + q];
            float4 wa = w3v[2 * (j0 + q) + 0];
            float4 wb = w3v[2 * (j0 + q) + 1];
            float h;
            h = fmaxf(fmaf(Pv.x, z1, Qv.x), 0.0f); sh = fmaf(h, wa.x, sh); sc = fmaf(h, wa.y, sc);
            h = fmaxf(fmaf(Pv.y, z1, Qv.y), 0.0f); sh = fmaf(h, wa.z, sh); sc = fmaf(h, wa.w, sc);
            h = fmaxf(fmaf(Pv.z, z1, Qv.z), 0.0f); sh = fmaf(h, wb.x, sh); sc = fmaf(h, wb.y, sc);
            h = fmaxf(fmaf(Pv.w, z1, Qv.w), 0.0f); sh = fmaf(h, wb.z, sh); sc = fmaf(h, wb.w, sc);
        }
        sh += __shfl_xor(sh, 1, 64);
        sc += __shfl_xor(sc, 1, 64);
        const float shift = sh + b3s[0];
        const float scale = sc + b3s[1];

        float z2n = (z2 - shift) * __expf(-scale);

        bool in2 = (fabsf(za) < LIMIT) && (fabsf(zb) < LIMIT);
        mask = mask && in2;
        if (mask) {
            za = fminf(fmaxf(z1,  -CLAMPV), CLAMPV);
            zb = fminf(fmaxf(z2n, -CLAMPV), CLAMPV);
            ld -= scale;
        }
    }

    // base log-prob; count each point once (even lane only)
    const float l0 = loc[0], l1 = loc[1];
    const float ls0 = log_scale[0], ls1 = log_scale[1];
    const float e0 = __expf(-ls0), e1 = __expf(-ls1);
    const float t0 = (za - l0) * e0, t1 = (zb - l1) * e1;
    float val = -1.8378770664093453f - (ls0 + ls1)
                - 0.5f * (t0 * t0 + t1 * t1) + ld;
    if (half) val = 0.0f;

    #pragma unroll
    for (int off = 32; off > 0; off >>= 1)
        val += __shfl_down(val, off, 64);

    const int wave = tid >> 6;
    if ((tid & 63) == 0) red[wave] = val;
    __syncthreads();
    if (tid == 0) {
        float ssum = red[0] + red[1] + red[2] + red[3];
        atomicAdd(out, ssum);
    }
}

extern "C" void kernel_launch(void* const* d_in, const int* in_sizes, int n_in,
                              void* d_out, int out_size, void* d_ws, size_t ws_size,
                              hipStream_t stream) {
    const float* x   = (const float*)d_in[0];
    const float* W1  = (const float*)d_in[1];
    const float* b1  = (const float*)d_in[2];
    const float* W2  = (const float*)d_in[3];
    const float* b2  = (const float*)d_in[4];
    const float* W3  = (const float*)d_in[5];
    const float* b3  = (const float*)d_in[6];
    const float* loc = (const float*)d_in[7];
    const float* lsc = (const float*)d_in[8];
    float* out = (float*)d_out;
    float* ws  = (float*)d_ws;

    zero_out_kernel<<<1, 1, 0, stream>>>(out);
    build_tables<<<NB, 256, 0, stream>>>(W1, b1, W2, b2, ws);
    realnvp_pwl<<<NPTS * 2 / 256, 256, 0, stream>>>(
        x, ws, W3, b3, loc, lsc, out);
}

// Round 4
// 221.191 us; speedup vs baseline: 3.6879x; 1.5857x over previous
//
#include <hip/hip_runtime.h>
#include <hip/hip_fp16.h>
#include <math.h>

#define NPTS   131072
#define NB     32
#define HD     64
#define NSEG   65            // 64 breakpoints -> 65 segments
#define ROWD   68            // padded LDS row stride in dwords (break bank aliasing)
#define LIMIT  10.0f
#define CLAMPV 10000.0f

// ws layout: tabG[NB][NSEG][HD] uint (half2{P,Q}) then bounds[NB][HD] float
#define TAB_UINTS   (NB * NSEG * HD)
#define BOUNDS_OFF  TAB_UINTS

// One workgroup per flow block: build piecewise-linear tables (fp16-packed).
// Also zeroes the output accumulator (block 0).
__global__ __launch_bounds__(256) void build_tables(
    const float* __restrict__ W1, const float* __restrict__ b1,
    const float* __restrict__ W2, const float* __restrict__ b2,
    float* __restrict__ ws, float* __restrict__ out)
{
    const int p = blockIdx.x;
    const int tid = threadIdx.x;

    if (p == 0 && tid == 0) out[0] = 0.0f;

    __shared__ float w1s[HD], b1s[HD], b2s[HD];
    __shared__ float tr[HD];        // raw breakpoints
    __shared__ float ts[HD];        // sorted breakpoints
    __shared__ float zrep[NSEG];    // per-segment representative point
    __shared__ float W2s[HD * HD];  // 16 KB

    for (int i = tid; i < HD * HD; i += 256)
        W2s[i] = W2[p * HD * HD + i];
    if (tid < HD) {
        w1s[tid] = W1[p * HD + tid];
        b1s[tid] = b1[p * HD + tid];
        b2s[tid] = b2[p * HD + tid];
    }
    __syncthreads();

    if (tid < HD) {
        float w = w1s[tid], b = b1s[tid];
        float t = -b / w;                 // +-inf when w==0 (unit never crosses)
        if (!(t == t)) t = INFINITY;      // NaN (b=w=0) -> push to end
        tr[tid] = t;
    }
    __syncthreads();
    if (tid < HD) {                       // rank sort (stable)
        float v = tr[tid];
        int r = 0;
        for (int j = 0; j < HD; ++j) {
            float u = tr[j];
            r += (u < v) || (u == v && j < tid);
        }
        ts[r] = v;
    }
    __syncthreads();
    if (tid < NSEG) {                     // representative z per segment
        float lo = (tid == 0)  ? -3.0e38f : ts[tid - 1];
        float hi = (tid == HD) ?  3.0e38f : ts[tid];
        lo = fmaxf(lo, -1.0e20f);         // keep finite: avoid 0*inf NaN
        hi = fminf(hi,  1.0e20f);
        zrep[tid] = 0.5f * (lo + hi);
    }
    __syncthreads();

    unsigned int* tabG = (unsigned int*)ws;
    for (int task = tid; task < NSEG * HD; task += 256) {
        const int s = task >> 6;
        const int j = task & (HD - 1);
        const float z = zrep[s];
        float Pv = 0.0f, Qv = b2s[j];
        for (int k = 0; k < HD; ++k) {
            float w = w1s[k], b = b1s[k];
            bool act = (fmaf(w, z, b) > 0.0f);
            float wij = W2s[k * HD + j];
            if (act) {
                Pv = fmaf(wij, w, Pv);
                Qv = fmaf(wij, b, Qv);
            }
        }
        __half2 hv = __halves2half2(__float2half_rn(Pv), __float2half_rn(Qv));
        tabG[((size_t)p * NSEG + s) * HD + j] = *(const unsigned int*)&hv;
    }
    if (tid < HD) ws[BOUNDS_OFF + p * HD + tid] = ts[tid];
}

// Two lanes per point (half = tid&1 handles 32 of 64 hidden channels).
// Per flow block, the fp16 P/Q table is staged in LDS with padded rows.
__global__ __launch_bounds__(256) void realnvp_pwl(
    const float* __restrict__ x,
    const float* __restrict__ ws,
    const float* __restrict__ W3, const float* __restrict__ b3,
    const float* __restrict__ loc, const float* __restrict__ log_scale,
    float* __restrict__ out)
{
    __shared__ __align__(16) unsigned int tab[NSEG * ROWD];  // 17.7 KB
    __shared__ float bt[HD];
    __shared__ float w3s[2 * HD];
    __shared__ float b3v[2];
    __shared__ float red[4];

    const int tid  = threadIdx.x;
    const int half = tid & 1;
    const int g    = blockIdx.x * 128 + (tid >> 1);

    const unsigned int* tabG = (const unsigned int*)ws;

    float za = x[2 * g + 0];
    float zb = x[2 * g + 1];
    float ld = 0.0f;
    bool mask = true;

    for (int t = 0; t < NB; ++t) {
        const int p = NB - 1 - t;

        __syncthreads();   // previous iteration's LDS reads done
        {
            const uint4* gsrc = (const uint4*)(tabG + (size_t)p * NSEG * HD);
            #pragma unroll
            for (int i = tid; i < NSEG * HD / 4; i += 256) {
                const int s = i >> 4, c = i & 15;
                uint4 v = gsrc[i];
                *((uint4*)&tab[s * ROWD + c * 4]) = v;
            }
            if (tid < HD)     bt[tid]  = ws[BOUNDS_OFF + p * HD + tid];
            if (tid < 2 * HD) w3s[tid] = W3[p * 2 * HD + tid];
            if (tid < 2)      b3v[tid] = b3[p * 2 + tid];
        }
        __syncthreads();

        // permute step
        bool in1 = (fabsf(za) < LIMIT) && (fabsf(zb) < LIMIT);
        mask = mask && in1;
        if (mask) {
            float na = fminf(fmaxf(zb, -CLAMPV), CLAMPV);
            float nb = fminf(fmaxf(za, -CLAMPV), CLAMPV);
            za = na; zb = nb;
        }

        const float z1 = za, z2 = zb;

        // segment = #breakpoints < z1; first 2 levels from hoisted values
        const float b31 = bt[31], b15 = bt[15], b47 = bt[47];
        int s = (b31 < z1) ? 32 : 0;
        const float l2 = (b31 < z1) ? b47 : b15;
        s += (l2 < z1) ? 16 : 0;
        #pragma unroll
        for (int st = 8; st > 0; st >>= 1)
            if (bt[s + st - 1] < z1) s += st;

        const uint4*  row = (const uint4*)&tab[s * ROWD + half * 32];
        const float4* w3q = (const float4*)&w3s[half * 64];

        float sh = 0.0f, sc = 0.0f;
        #pragma unroll
        for (int q = 0; q < 8; ++q) {
            uint4 v = row[q];
            float4 wa = w3q[2 * q + 0];
            float4 wb = w3q[2 * q + 1];
            float2 f; float h;
            f = __half22float2(*(const __half2*)&v.x);
            h = fmaxf(fmaf(f.x, z1, f.y), 0.0f); sh = fmaf(h, wa.x, sh); sc = fmaf(h, wa.y, sc);
            f = __half22float2(*(const __half2*)&v.y);
            h = fmaxf(fmaf(f.x, z1, f.y), 0.0f); sh = fmaf(h, wa.z, sh); sc = fmaf(h, wa.w, sc);
            f = __half22float2(*(const __half2*)&v.z);
            h = fmaxf(fmaf(f.x, z1, f.y), 0.0f); sh = fmaf(h, wb.x, sh); sc = fmaf(h, wb.y, sc);
            f = __half22float2(*(const __half2*)&v.w);
            h = fmaxf(fmaf(f.x, z1, f.y), 0.0f); sh = fmaf(h, wb.z, sh); sc = fmaf(h, wb.w, sc);
        }
        sh += __shfl_xor(sh, 1, 64);
        sc += __shfl_xor(sc, 1, 64);
        const float shift = sh + b3v[0];
        const float scale = sc + b3v[1];

        float z2n = (z2 - shift) * __expf(-scale);

        bool in2 = (fabsf(za) < LIMIT) && (fabsf(zb) < LIMIT);
        mask = mask && in2;
        if (mask) {
            za = fminf(fmaxf(z1,  -CLAMPV), CLAMPV);
            zb = fminf(fmaxf(z2n, -CLAMPV), CLAMPV);
            ld -= scale;
        }
    }

    // base log-prob; count each point once (even lane only)
    const float l0 = loc[0], l1 = loc[1];
    const float ls0 = log_scale[0], ls1 = log_scale[1];
    const float e0 = __expf(-ls0), e1 = __expf(-ls1);
    const float t0 = (za - l0) * e0, t1 = (zb - l1) * e1;
    float val = -1.8378770664093453f - (ls0 + ls1)
                - 0.5f * (t0 * t0 + t1 * t1) + ld;
    if (half) val = 0.0f;

    #pragma unroll
    for (int off = 32; off > 0; off >>= 1)
        val += __shfl_down(val, off, 64);

    const int wave = tid >> 6;
    if ((tid & 63) == 0) red[wave] = val;
    __syncthreads();
    if (tid == 0) {
        float ssum = red[0] + red[1] + red[2] + red[3];
        atomicAdd(out, ssum);
    }
}

extern "C" void kernel_launch(void* const* d_in, const int* in_sizes, int n_in,
                              void* d_out, int out_size, void* d_ws, size_t ws_size,
                              hipStream_t stream) {
    const float* x   = (const float*)d_in[0];
    const float* W1  = (const float*)d_in[1];
    const float* b1  = (const float*)d_in[2];
    const float* W2  = (const float*)d_in[3];
    const float* b2  = (const float*)d_in[4];
    const float* W3  = (const float*)d_in[5];
    const float* b3  = (const float*)d_in[6];
    const float* loc = (const float*)d_in[7];
    const float* lsc = (const float*)d_in[8];
    float* out = (float*)d_out;
    float* ws  = (float*)d_ws;

    build_tables<<<NB, 256, 0, stream>>>(W1, b1, W2, b2, ws, out);
    realnvp_pwl<<<NPTS * 2 / 256, 256, 0, stream>>>(
        x, ws, W3, b3, loc, lsc, out);
}

// Round 5
// 160.266 us; speedup vs baseline: 5.0898x; 1.3802x over previous
//
#include <hip/hip_runtime.h>
#include <hip/hip_fp16.h>
#include <math.h>

#define NPTS   131072
#define NB     32
#define HD     64
#define NSEG   65            // 64 coarse breakpoints -> 65 coarse segments
#define CAP    1024          // refined breakpoints per block (padded +INF)
#define LIMIT  10.0f
#define CLAMPV 10000.0f

// ws layout: ABCD float4[NB][CAP+1]  (525 KB)  then T half[NB][CAP] (64 KB)
#define T_OFF_FLOATS  (NB * (CAP + 1) * 4)

// One workgroup per flow block: exact piecewise-linear collapse of the MLP.
__global__ __launch_bounds__(512) void build_tables(
    const float* __restrict__ W1, const float* __restrict__ b1,
    const float* __restrict__ W2, const float* __restrict__ b2,
    const float* __restrict__ W3, const float* __restrict__ b3,
    float* __restrict__ ws, float* __restrict__ out)
{
    const int p = blockIdx.x;
    const int tid = threadIdx.x;
    if (p == 0 && tid == 0) out[0] = 0.0f;

    __shared__ float w1s[HD], b1s[HD], b2s[HD], w3a[HD], w3b[HD];
    __shared__ float W2s[HD * HD];          // 16 KB
    __shared__ float trC[HD], tsC[HD], zrepC[NSEG];
    __shared__ float Ps[NSEG * HD], Qs[NSEG * HD];   // 33.3 KB
    __shared__ float buf[CAP], Ts[CAP];     // 8 KB
    __shared__ int cnt;

    for (int i = tid; i < HD * HD; i += 512) W2s[i] = W2[p * HD * HD + i];
    if (tid < HD) {
        w1s[tid] = W1[p * HD + tid];
        b1s[tid] = b1[p * HD + tid];
        b2s[tid] = b2[p * HD + tid];
        w3a[tid] = W3[p * 2 * HD + 2 * tid + 0];
        w3b[tid] = W3[p * 2 * HD + 2 * tid + 1];
    }
    if (tid == 0) cnt = 0;
    __syncthreads();

    // coarse breakpoints
    if (tid < HD) {
        float w = w1s[tid], b = b1s[tid];
        float t = -b / w;                 // +-inf when w==0
        if (!(t == t)) t = INFINITY;      // NaN -> +inf
        trC[tid] = t;
    }
    __syncthreads();
    if (tid < HD) {                       // rank sort 64 (stable)
        float v = trC[tid];
        int r = 0;
        for (int j = 0; j < HD; ++j) {
            float u = trC[j];
            r += (u < v) || (u == v && j < tid);
        }
        tsC[r] = v;
    }
    __syncthreads();
    if (tid < NSEG) {
        float lo = (tid == 0)  ? -3.0e38f : tsC[tid - 1];
        float hi = (tid == HD) ?  3.0e38f : tsC[tid];
        lo = fmaxf(lo, -1.0e20f);
        hi = fminf(hi,  1.0e20f);
        zrepC[tid] = 0.5f * (lo + hi);
    }
    __syncthreads();

    // per (coarse segment, channel): layer-2 preactivation = P*z + Q
    for (int task = tid; task < NSEG * HD; task += 512) {
        const int s = task >> 6, j = task & (HD - 1);
        const float z = zrepC[s];
        float Pv = 0.0f, Qv = b2s[j];
        for (int k = 0; k < HD; ++k) {
            float w = w1s[k], b = b1s[k];
            if (fmaf(w, z, b) > 0.0f) {
                float wij = W2s[k * HD + j];
                Pv = fmaf(wij, w, Pv);
                Qv = fmaf(wij, b, Qv);
            }
        }
        Ps[task] = Pv; Qs[task] = Qv;
    }
    __syncthreads();

    // collect refined breakpoints: all coarse + layer-2 zero crossings
    if (tid < HD) {
        int i = atomicAdd(&cnt, 1);
        if (i < CAP) buf[i] = tsC[tid];
    }
    for (int task = tid; task < NSEG * HD; task += 512) {
        const int s = task >> 6;
        float Pv = Ps[task], Qv = Qs[task];
        if (Pv != 0.0f) {
            float zc = -Qv / Pv;
            float lo = (s == 0)  ? -INFINITY : tsC[s - 1];
            float hi = (s == HD) ?  INFINITY : tsC[s];
            if (zc > lo && zc < hi) {
                int i = atomicAdd(&cnt, 1);
                if (i < CAP) buf[i] = zc;
            }
        }
    }
    __syncthreads();
    const int n = min(cnt, CAP);

    // rank sort n refined breakpoints
    for (int i = tid; i < n; i += 512) {
        float v = buf[i];
        int r = 0;
        for (int j = 0; j < n; ++j) {
            float u = buf[j];
            r += (u < v) || (u == v && j < i);
        }
        Ts[r] = v;
    }
    __syncthreads();

    // write fp16 breakpoint table (padded +inf)
    unsigned short* Tg = (unsigned short*)(ws + T_OFF_FLOATS);
    for (int i = tid; i < CAP; i += 512) {
        unsigned short hv = 0x7C00;       // +inf
        if (i < n) {
            __half h = __float2half_rn(Ts[i]);
            hv = *(const unsigned short*)&h;
        }
        Tg[p * CAP + i] = hv;
    }

    // ABCD per interval u in [0, n]
    const float b30 = b3[p * 2 + 0], b31 = b3[p * 2 + 1];
    float4* AB = (float4*)ws;
    for (int u = tid; u <= n; u += 512) {
        float lo = (u == 0) ? -1.0e20f : fmaxf(Ts[u - 1], -1.0e20f);
        float hi = (u == n) ?  1.0e20f : fminf(Ts[u],  1.0e20f);
        float zm = 0.5f * (lo + hi);
        int s = 0;
        for (int k = 0; k < HD; ++k) s += (tsC[k] < zm);
        float Ash = 0.f, Bsh = 0.f, Asc = 0.f, Bsc = 0.f;
        for (int j = 0; j < HD; ++j) {
            float Pv = Ps[s * HD + j], Qv = Qs[s * HD + j];
            if (fmaf(Pv, zm, Qv) > 0.0f) {
                Ash = fmaf(w3a[j], Pv, Ash); Bsh = fmaf(w3a[j], Qv, Bsh);
                Asc = fmaf(w3b[j], Pv, Asc); Bsc = fmaf(w3b[j], Qv, Bsc);
            }
        }
        AB[p * (CAP + 1) + u] = make_float4(Ash, Bsh + b30, Asc, Bsc + b31);
    }
}

// 1 lane per point. All 32 blocks' breakpoint tables live in LDS (64 KB,
// staged once); no per-step barriers. Paired-probe search: 5 dependent levels.
__global__ __launch_bounds__(256) void realnvp_pwl(
    const float* __restrict__ x,
    const float* __restrict__ ws,
    const float* __restrict__ loc, const float* __restrict__ log_scale,
    float* __restrict__ out)
{
    __shared__ __align__(16) unsigned short Tl[NB * CAP];   // exactly 64 KB

    const int tid = threadIdx.x;
    const int g = blockIdx.x * 256 + tid;

    {   // stage all breakpoint tables once
        const uint4* Tg4 = (const uint4*)((const unsigned short*)(ws + T_OFF_FLOATS));
        uint4* Tl4 = (uint4*)Tl;
        #pragma unroll
        for (int i = tid; i < NB * CAP / 8; i += 256) Tl4[i] = Tg4[i];
    }
    __syncthreads();

    const float4* AB = (const float4*)ws;

    float2 xv = ((const float2*)x)[g];
    float za = xv.x, zb = xv.y;
    float ld = 0.0f;
    bool mask = true;

    for (int t = 0; t < NB; ++t) {
        const int p = NB - 1 - t;

        bool in1 = (fabsf(za) < LIMIT) && (fabsf(zb) < LIMIT);
        mask = mask && in1;
        if (mask) {
            float na = fminf(fmaxf(zb, -CLAMPV), CLAMPV);
            float nb = fminf(fmaxf(za, -CLAMPV), CLAMPV);
            za = na; zb = nb;
        }

        const float z1 = za, z2 = zb;

        // branchless binary search: u = #(T[p] < z1); two levels per probe
        const __half* Tp = (const __half*)&Tl[p << 10];
        int u = 0;
        #pragma unroll
        for (int st = 512; st >= 2; st >>= 2) {          // 512,128,32,8,2
            float a = __half2float(Tp[u + st - 1]);
            float bv = __half2float(Tp[u + (st >> 1) - 1]);
            float c = __half2float(Tp[u + st + (st >> 1) - 1]);
            bool gsel = (a < z1);
            u += gsel ? st : 0;
            float t2 = gsel ? c : bv;
            u += (t2 < z1) ? (st >> 1) : 0;
        }

        float4 abcd = AB[p * (CAP + 1) + u];
        const float shift = fmaf(abcd.x, z1, abcd.y);
        const float scale = fmaf(abcd.z, z1, abcd.w);
        float z2n = (z2 - shift) * __expf(-scale);

        bool in2 = (fabsf(za) < LIMIT) && (fabsf(zb) < LIMIT);
        mask = mask && in2;
        if (mask) {
            za = fminf(fmaxf(z1,  -CLAMPV), CLAMPV);
            zb = fminf(fmaxf(z2n, -CLAMPV), CLAMPV);
            ld -= scale;
        }
    }

    // base log-prob
    const float l0 = loc[0], l1 = loc[1];
    const float ls0 = log_scale[0], ls1 = log_scale[1];
    const float e0 = __expf(-ls0), e1 = __expf(-ls1);
    const float t0 = (za - l0) * e0, t1 = (zb - l1) * e1;
    float val = -1.8378770664093453f - (ls0 + ls1)
                - 0.5f * (t0 * t0 + t1 * t1) + ld;

    // wave reduction + one atomic per wave (no extra LDS: Tl is exactly 64 KB)
    #pragma unroll
    for (int off = 32; off > 0; off >>= 1)
        val += __shfl_down(val, off, 64);
    if ((tid & 63) == 0) atomicAdd(out, val);
}

extern "C" void kernel_launch(void* const* d_in, const int* in_sizes, int n_in,
                              void* d_out, int out_size, void* d_ws, size_t ws_size,
                              hipStream_t stream) {
    const float* x   = (const float*)d_in[0];
    const float* W1  = (const float*)d_in[1];
    const float* b1  = (const float*)d_in[2];
    const float* W2  = (const float*)d_in[3];
    const float* b2  = (const float*)d_in[4];
    const float* W3  = (const float*)d_in[5];
    const float* b3  = (const float*)d_in[6];
    const float* loc = (const float*)d_in[7];
    const float* lsc = (const float*)d_in[8];
    float* out = (float*)d_out;
    float* ws  = (float*)d_ws;

    build_tables<<<NB, 512, 0, stream>>>(W1, b1, W2, b2, W3, b3, ws, out);
    realnvp_pwl<<<NPTS / 256, 256, 0, stream>>>(x, ws, loc, lsc, out);
}

// Round 6
// 155.269 us; speedup vs baseline: 5.2536x; 1.0322x over previous
//
#include <hip/hip_runtime.h>
#include <hip/hip_fp16.h>
#include <math.h>

#define NPTS   131072
#define NB     32
#define HD     64
#define NSEG   65
#define CAPN   511           // max refined breakpoints kept (rank fits 3x 8-ary levels)
#define LIMIT  10.0f
#define RANGE  10.001f       // breakpoint filter window (only |z1|<10 matters)
#define CLAMPV 10000.0f

// per-block tree: 73 nodes x 8 halfs (level0:1, level1:8, level2:64) = 584 halfs
#define TREEH   584
// ws layout: AB float4[NB][512] (256 KB) then tree u16[NB][TREEH] (37376 B)
#define AB_BYTES (NB * 512 * 16)

// ---------------- build: exact piecewise-linear collapse of each MLP ----------------
__global__ __launch_bounds__(512) void build_tables(
    const float* __restrict__ W1, const float* __restrict__ b1,
    const float* __restrict__ W2, const float* __restrict__ b2,
    const float* __restrict__ W3, const float* __restrict__ b3,
    float* __restrict__ ws, float* __restrict__ out)
{
    const int p = blockIdx.x;
    const int tid = threadIdx.x;
    if (p == 0 && tid == 0) out[0] = 0.0f;

    __shared__ float w1s[HD], b1s[HD], b2s[HD], w3a[HD], w3b[HD];
    __shared__ float W2s[HD * HD];              // 16 KB
    __shared__ float trC[HD], tsC[HD];
    __shared__ int   ksC[HD];
    __shared__ float Ps[NSEG * HD], Qs[NSEG * HD];   // 33.3 KB
    __shared__ float bufB[CAPN + 1], Ts[CAPN + 1];
    __shared__ int cnt;

    for (int i = tid; i < HD * HD; i += 512) W2s[i] = W2[p * HD * HD + i];
    if (tid < HD) {
        w1s[tid] = W1[p * HD + tid];
        b1s[tid] = b1[p * HD + tid];
        b2s[tid] = b2[p * HD + tid];
        w3a[tid] = W3[p * 2 * HD + 2 * tid + 0];
        w3b[tid] = W3[p * 2 * HD + 2 * tid + 1];
    }
    if (tid == 0) cnt = 0;
    __syncthreads();

    // coarse kinks t_k = -b/w  (w==0 -> +inf: never crossed)
    if (tid < HD) {
        float w = w1s[tid], b = b1s[tid];
        float t = (w != 0.0f) ? (-b / w) : INFINITY;
        if (!(t == t)) t = INFINITY;
        trC[tid] = t;
    }
    __syncthreads();
    if (tid < HD) {                       // stable rank sort of 64 (t, k)
        float v = trC[tid];
        int r = 0;
        for (int j = 0; j < HD; ++j) {
            float u = trC[j];
            r += (u < v) || (u == v && j < tid);
        }
        tsC[r] = v; ksC[r] = tid;
    }
    __syncthreads();

    // prefix-sweep P/Q per channel j: P_j(s), Q_j(s) for s = #kinks below z
    if (tid < HD) {
        const int j = tid;
        float Pv = 0.0f, Qv = b2s[j];
        for (int k = 0; k < HD; ++k) {    // active at z = -inf
            float w = w1s[k], b = b1s[k];
            bool act = (w < 0.0f) || (w == 0.0f && b > 0.0f);
            if (act) {
                float wij = W2s[k * HD + j];
                Pv = fmaf(wij, w, Pv);
                Qv = fmaf(wij, b, Qv);
            }
        }
        Ps[j] = Pv; Qs[j] = Qv;
        for (int s = 1; s <= HD; ++s) {   // cross sorted kink s-1
            const int k = ksC[s - 1];
            const float w = w1s[k];
            if (w != 0.0f && isfinite(tsC[s - 1])) {
                float sgn = (w > 0.0f) ? 1.0f : -1.0f;
                float wij = W2s[k * HD + j];
                Pv = fmaf(sgn * wij, w,       Pv);
                Qv = fmaf(sgn * wij, b1s[k],  Qv);
            }
            Ps[s * HD + j] = Pv; Qs[s * HD + j] = Qv;
        }
    }
    __syncthreads();

    // collect refined breakpoints within (-RANGE, RANGE)
    if (tid < HD) {
        float t = tsC[tid];
        if (t > -RANGE && t < RANGE) {
            int i = atomicAdd(&cnt, 1);
            if (i < CAPN) bufB[i] = t;
        }
    }
    for (int task = tid; task < NSEG * HD; task += 512) {
        const int s = task >> 6;
        float Pv = Ps[task], Qv = Qs[task];
        if (Pv != 0.0f) {
            float zc = -Qv / Pv;
            float lo = (s == 0)  ? -RANGE : fmaxf(tsC[s - 1], -RANGE);
            float hi = (s == HD) ?  RANGE : fminf(tsC[s],  RANGE);
            if (zc > lo && zc < hi) {
                int i = atomicAdd(&cnt, 1);
                if (i < CAPN) bufB[i] = zc;
            }
        }
    }
    __syncthreads();
    const int n = min(cnt, CAPN);

    for (int i = tid; i < n; i += 512) {  // stable rank sort n refined
        float v = bufB[i];
        int r = 0;
        for (int j = 0; j < n; ++j) {
            float u = bufB[j];
            r += (u < v) || (u == v && j < i);
        }
        Ts[r] = v;
    }
    __syncthreads();

    // emit fp16 8-ary search tree (ranks: L0 (j+1)*64-1; L1 (i*8+j+1)*8-1; L2 i*8+j)
    unsigned short* treeG = (unsigned short*)((char*)ws + AB_BYTES);
    for (int e = tid; e < TREEH; e += 512) {
        const int node = e >> 3, slot = e & 7;
        int r = -1;
        if (slot < 7) {
            if (node == 0)      r = (slot + 1) * 64 - 1;
            else if (node < 9)  r = ((node - 1) * 8 + slot + 1) * 8 - 1;
            else                r = (node - 9) * 8 + slot;
        }
        unsigned short hv = 0x7C00;       // +inf
        if (r >= 0 && r < n) {
            __half h = __float2half_rn(Ts[r]);
            hv = *(const unsigned short*)&h;
        }
        treeG[p * TREEH + e] = hv;
    }

    // ABCD per interval u in [0, n]
    const float b30 = b3[p * 2 + 0], b31 = b3[p * 2 + 1];
    float4* AB = (float4*)ws;
    for (int u = tid; u <= n; u += 512) {
        float lo = (u == 0) ? -RANGE : Ts[u - 1];
        float hi = (u == n) ?  RANGE : Ts[u];
        float zm = 0.5f * (lo + hi);
        int s = 0;
        for (int k = 0; k < HD; ++k) s += (tsC[k] < zm);
        float Ash = 0.f, Bsh = 0.f, Asc = 0.f, Bsc = 0.f;
        for (int j = 0; j < HD; ++j) {
            float Pv = Ps[s * HD + j], Qv = Qs[s * HD + j];
            if (fmaf(Pv, zm, Qv) > 0.0f) {
                Ash = fmaf(w3a[j], Pv, Ash); Bsh = fmaf(w3a[j], Qv, Bsh);
                Asc = fmaf(w3b[j], Pv, Asc); Bsc = fmaf(w3b[j], Qv, Bsc);
            }
        }
        AB[(p << 9) + u] = make_float4(Ash, Bsh + b30, Asc, Bsc + b31);
    }
}

// ---------------- eval: 2 points per lane, 3-round 8-ary LDS tree search ----------------
__device__ __forceinline__ int count8(const unsigned short* node, float z1) {
    uint4 v = *(const uint4*)node;       // 8 fp16 keys (slot 7 = +inf pad)
    unsigned int w[4] = {v.x, v.y, v.z, v.w};
    int c = 0;
    #pragma unroll
    for (int q = 0; q < 4; ++q) {
        __half2 h2 = *(const __half2*)&w[q];
        c += (__low2float(h2)  < z1);
        c += (__high2float(h2) < z1);
    }
    return c;
}

__global__ __launch_bounds__(128) void realnvp_pwl(
    const float* __restrict__ x,
    const float* __restrict__ ws,
    const float* __restrict__ loc, const float* __restrict__ log_scale,
    float* __restrict__ out)
{
    __shared__ __align__(16) unsigned short tree[NB * TREEH];   // 36.5 KB

    const int tid = threadIdx.x;
    {   // stage all 32 trees once
        const uint4* tg = (const uint4*)((const char*)ws + AB_BYTES);
        uint4* tl = (uint4*)tree;
        for (int i = tid; i < NB * TREEH / 8; i += 128) tl[i] = tg[i];
    }
    __syncthreads();

    const float4* AB = (const float4*)ws;
    const int g = blockIdx.x * 128 + tid;       // lane owns points 2g, 2g+1

    float4 xv = ((const float4*)x)[g];
    float za[2] = {xv.x, xv.z};
    float zb[2] = {xv.y, xv.w};
    float ld[2] = {0.0f, 0.0f};
    bool  mk[2] = {true, true};

    for (int t = 0; t < NB; ++t) {
        const int p = NB - 1 - t;
        const unsigned short* bp = tree + p * TREEH;

        float z1v[2], z2v[2];
        int   uv[2];
        #pragma unroll
        for (int k = 0; k < 2; ++k) {
            bool in1 = (fabsf(za[k]) < LIMIT) && (fabsf(zb[k]) < LIMIT);
            mk[k] = mk[k] && in1;
            if (mk[k]) {
                float na = fminf(fmaxf(zb[k], -CLAMPV), CLAMPV);
                float nb = fminf(fmaxf(za[k], -CLAMPV), CLAMPV);
                za[k] = na; zb[k] = nb;
            }
            z1v[k] = za[k]; z2v[k] = zb[k];
        }
        #pragma unroll
        for (int k = 0; k < 2; ++k) {       // two independent search chains
            const float z1 = z1v[k];
            int c0 = count8(bp, z1);
            int c1 = count8(bp + 8 + c0 * 8, z1);
            int i2 = c0 * 8 + c1;
            int c2 = count8(bp + 72 + i2 * 8, z1);
            uv[k] = i2 * 8 + c2;
        }
        #pragma unroll
        for (int k = 0; k < 2; ++k) {
            float4 abcd = AB[(p << 9) + uv[k]];
            const float shift = fmaf(abcd.x, z1v[k], abcd.y);
            const float scale = fmaf(abcd.z, z1v[k], abcd.w);
            float z2n = (z2v[k] - shift) * __expf(-scale);

            bool in2 = (fabsf(za[k]) < LIMIT) && (fabsf(zb[k]) < LIMIT);
            mk[k] = mk[k] && in2;
            if (mk[k]) {
                za[k] = fminf(fmaxf(z1v[k], -CLAMPV), CLAMPV);
                zb[k] = fminf(fmaxf(z2n,   -CLAMPV), CLAMPV);
                ld[k] -= scale;
            }
        }
    }

    const float l0 = loc[0], l1 = loc[1];
    const float ls0 = log_scale[0], ls1 = log_scale[1];
    const float e0 = __expf(-ls0), e1 = __expf(-ls1);
    float val = 0.0f;
    #pragma unroll
    for (int k = 0; k < 2; ++k) {
        const float t0 = (za[k] - l0) * e0, t1 = (zb[k] - l1) * e1;
        val += -1.8378770664093453f - (ls0 + ls1)
               - 0.5f * (t0 * t0 + t1 * t1) + ld[k];
    }

    #pragma unroll
    for (int off = 32; off > 0; off >>= 1)
        val += __shfl_down(val, off, 64);
    if ((tid & 63) == 0) atomicAdd(out, val);
}

extern "C" void kernel_launch(void* const* d_in, const int* in_sizes, int n_in,
                              void* d_out, int out_size, void* d_ws, size_t ws_size,
                              hipStream_t stream) {
    const float* x   = (const float*)d_in[0];
    const float* W1  = (const float*)d_in[1];
    const float* b1  = (const float*)d_in[2];
    const float* W2  = (const float*)d_in[3];
    const float* b2  = (const float*)d_in[4];
    const float* W3  = (const float*)d_in[5];
    const float* b3  = (const float*)d_in[6];
    const float* loc = (const float*)d_in[7];
    const float* lsc = (const float*)d_in[8];
    float* out = (float*)d_out;
    float* ws  = (float*)d_ws;

    build_tables<<<NB, 512, 0, stream>>>(W1, b1, W2, b2, W3, b3, ws, out);
    realnvp_pwl<<<NPTS / 256, 128, 0, stream>>>(x, ws, loc, lsc, out);
}